// Round 8
// baseline (231.785 us; speedup 1.0000x reference)
//
#include <hip/hip_runtime.h>

typedef __attribute__((ext_vector_type(4))) float f32x4;
typedef __attribute__((ext_vector_type(16))) float f32x16;
typedef __attribute__((ext_vector_type(4))) unsigned short u16x4;
typedef __attribute__((ext_vector_type(8))) unsigned short u16x8;
typedef __attribute__((ext_vector_type(4))) unsigned int u32x4;
typedef __attribute__((ext_vector_type(8))) __bf16 bf16x8;

__device__ __forceinline__ unsigned short f2bf(float f) {
  unsigned int u = __builtin_bit_cast(unsigned int, f);
  u += 0x7fffu + ((u >> 16) & 1u);
  return (unsigned short)(u >> 16);
}

__device__ __forceinline__ bf16x8 ld_bf8(const unsigned short* p) {
  return __builtin_bit_cast(bf16x8, *(const u16x8*)p);
}

__device__ __forceinline__ f32x4 mfma16(bf16x8 a, bf16x8 b, f32x4 c) {
  return __builtin_amdgcn_mfma_f32_16x16x32_bf16(a, b, c, 0, 0, 0);
}

__device__ __forceinline__ f32x16 mfma32(bf16x8 a, bf16x8 b, f32x16 c) {
  return __builtin_amdgcn_mfma_f32_32x32x16_bf16(a, b, c, 0, 0, 0);
}

__device__ __forceinline__ unsigned int cvt_pk_bf16(float lo, float hi) {
  unsigned int r;
  asm("v_cvt_pk_bf16_f32 %0, %1, %2" : "=v"(r) : "v"(lo), "v"(hi));
  return r;
}

__device__ __forceinline__ void plane32_swap(unsigned int& a, unsigned int& b) {
  asm("v_permlane32_swap_b32 %0, %1" : "+v"(a), "+v"(b));
}

// ---------------- fp32 -> bf16 convert ----------------
__global__ void cvt_kernel(const float* __restrict__ in,
                           unsigned short* __restrict__ out, int n) {
  int i = (blockIdx.x * 256 + threadIdx.x) * 4;
  if (i >= n) return;
  f32x4 v = *(const f32x4*)(in + i);
  u16x4 r;
  r[0] = f2bf(v[0]); r[1] = f2bf(v[1]); r[2] = f2bf(v[2]); r[3] = f2bf(v[3]);
  *(u16x4*)(out + i) = r;
}

// ---------------- GEMM: C[m,n] = sum_k A[m,k]*W[n,k] + bias[n] ----------------
template <int EPI>
__global__ __launch_bounds__(256) void gemm_bt(const unsigned short* __restrict__ A,
                                               const unsigned short* __restrict__ Bw,
                                               const float* __restrict__ bias,
                                               void* __restrict__ Cout) {
  const int l = threadIdx.x & 63;
  const int w = threadIdx.x >> 6;
  const int g = l >> 4;
  const int lr = l & 15;
  const int m0 = blockIdx.y * 128 + (w >> 1) * 64;
  const int n0 = blockIdx.x * 128 + (w & 1) * 64;

  f32x4 acc[4][4];
#pragma unroll
  for (int i = 0; i < 4; i++)
#pragma unroll
    for (int j = 0; j < 4; j++) acc[i][j] = f32x4{0.f, 0.f, 0.f, 0.f};

  const unsigned short* pA = A + (size_t)(m0 + lr) * 512 + g * 8;
  const unsigned short* pB = Bw + (size_t)(n0 + lr) * 512 + g * 8;

  for (int k = 0; k < 512; k += 32) {
    bf16x8 af[4], bfr[4];
#pragma unroll
    for (int t = 0; t < 4; t++) af[t] = ld_bf8(pA + t * (16 * 512) + k);
#pragma unroll
    for (int t = 0; t < 4; t++) bfr[t] = ld_bf8(pB + t * (16 * 512) + k);
#pragma unroll
    for (int i = 0; i < 4; i++)
#pragma unroll
      for (int j = 0; j < 4; j++)
        acc[i][j] = mfma16(af[i], bfr[j], acc[i][j]);
  }

#pragma unroll
  for (int j = 0; j < 4; j++) {
    const int n = n0 + j * 16 + lr;
    const float bn = bias[n];
#pragma unroll
    for (int i = 0; i < 4; i++) {
#pragma unroll
      for (int r = 0; r < 4; r++) {
        const int m = m0 + i * 16 + g * 4 + r;
        const float v = acc[i][j][r] + bn;
        if (EPI == 0) {
          ((unsigned short*)Cout)[(size_t)m * 512 + n] = f2bf(v);
        } else if (EPI == 1) {
          const int bb = m >> 11, s = m & 2047;
          const int hh = n >> 6, d = n & 63;
          ((unsigned short*)Cout)[((size_t)((bb * 8 + hh) * 64 + d) << 11) + s] = f2bf(v);
        } else {
          ((float*)Cout)[(size_t)m * 512 + n] = v;
        }
      }
    }
  }
}

// ---------------- flash attention, intra-block split-KV (4 waves), 32x32 MFMA ----------------
// Qp/Kp: [B*2048, 512] bf16 (head slice at h*64). Vt: [B,H,64,2048] bf16.
// Block = 4 waves, 32 q-rows TOTAL; wave w handles KV range [w*512,(w+1)*512).
// Partials (unnormalized O + m,l) combined in LDS -> bf16 At. No global partials.
__global__ __launch_bounds__(256, 2) void attn_kernel(const unsigned short* __restrict__ Qp,
                                                      const unsigned short* __restrict__ Kp,
                                                      const unsigned short* __restrict__ Vt,
                                                      const float* __restrict__ rel_emb,
                                                      unsigned short* __restrict__ At) {
  __shared__ float bias_s[257];
  __shared__ float o_lds[4][32][64];
  __shared__ float ml_lds[4][2][32];
  const int bid = blockIdx.x;
  const int qb = bid & 63;
  const int h = (bid >> 6) & 7;
  const int b = bid >> 9;
  const int tid = threadIdx.x;
  for (int i = tid; i < 257; i += 256) bias_s[i] = rel_emb[i * 8 + h] * 1.44269504f;
  __syncthreads();
  const float bias_lo = bias_s[0], bias_hi = bias_s[256];

  const int lane = tid & 63, w = tid >> 6;
  const int hi = lane >> 5, q31 = lane & 31;
  const int q0w = qb * 32;        // block's 32 q-rows (shared by all waves)
  const int tq = q0w + q31;
  const int s_base = w << 9;      // this wave's KV quarter
  const float SCL = 0.125f * 1.44269504f;  // 1/sqrt(64) * log2(e)

  const unsigned short* qptr = Qp + (size_t)(b * 2048 + tq) * 512 + h * 64 + hi * 8;
  const bf16x8 qf0 = ld_bf8(qptr);
  const bf16x8 qf1 = ld_bf8(qptr + 16);
  const bf16x8 qf2 = ld_bf8(qptr + 32);
  const bf16x8 qf3 = ld_bf8(qptr + 48);

  const unsigned short* kbase = Kp + (size_t)(b * 2048) * 512 + h * 64 + hi * 8;
  const unsigned short* vb_lo = Vt + (((size_t)((b * 8 + h) * 64 + q31)) << 11) + hi * 8;
  const unsigned short* vb_hi = vb_lo + ((size_t)32 << 11);

  const f32x16 z16 = {0.f, 0.f, 0.f, 0.f, 0.f, 0.f, 0.f, 0.f,
                      0.f, 0.f, 0.f, 0.f, 0.f, 0.f, 0.f, 0.f};
  f32x16 o_lo = z16, o_hi = z16;
  float m_run = -1e30f, l_run = 0.f;
  f32x16 sa, sb;

  auto softmax_part = [&](int s0) {
    const int relmin = q0w - s0 - 63;
    const int relmax = q0w + 31 - s0;
    if (relmin >= 128 || relmax <= -128) {
      const float bc = (relmin >= 128) ? bias_hi : bias_lo;
#pragma unroll
      for (int r = 0; r < 16; r++) {
        sa[r] = fmaf(sa[r], SCL, bc);
        sb[r] = fmaf(sb[r], SCL, bc);
      }
    } else {
#pragma unroll
      for (int r = 0; r < 16; r++) {
        const int rowA = (r & 3) + 8 * (r >> 2) + 4 * hi;
        const int rA = tq - s0 - rowA;
        const int rB = rA - 32;
        const int iA = (rA < -128 ? -128 : (rA > 128 ? 128 : rA)) + 128;
        const int iB = (rB < -128 ? -128 : (rB > 128 ? 128 : rB)) + 128;
        sa[r] = fmaf(sa[r], SCL, bias_s[iA]);
        sb[r] = fmaf(sb[r], SCL, bias_s[iB]);
      }
    }
    const float t0 = fmaxf(fmaxf(sa[0], sa[1]), sa[2]);
    const float t1 = fmaxf(fmaxf(sa[3], sa[4]), sa[5]);
    const float t2 = fmaxf(fmaxf(sa[6], sa[7]), sa[8]);
    const float t3 = fmaxf(fmaxf(sa[9], sa[10]), sa[11]);
    const float t4 = fmaxf(fmaxf(sa[12], sa[13]), sa[14]);
    const float t5 = fmaxf(fmaxf(sa[15], sb[0]), sb[1]);
    const float t6 = fmaxf(fmaxf(sb[2], sb[3]), sb[4]);
    const float t7 = fmaxf(fmaxf(sb[5], sb[6]), sb[7]);
    const float t8 = fmaxf(fmaxf(sb[8], sb[9]), sb[10]);
    const float t9 = fmaxf(fmaxf(sb[11], sb[12]), sb[13]);
    const float ta = fmaxf(sb[14], sb[15]);
    const float u0 = fmaxf(fmaxf(t0, t1), t2);
    const float u1 = fmaxf(fmaxf(t3, t4), t5);
    const float u2 = fmaxf(fmaxf(t6, t7), t8);
    float mx = fmaxf(fmaxf(fmaxf(u0, u1), u2), fmaxf(t9, ta));
    mx = fmaxf(mx, __shfl_xor(mx, 32, 64));

    if (!__all(mx <= m_run + 8.f)) {
      const float m_new = fmaxf(m_run, mx);
      const float rsq = exp2f(m_run - m_new);
      l_run *= rsq;
      m_run = m_new;
#pragma unroll
      for (int r2 = 0; r2 < 16; r2++) {
        const int ro = (r2 & 3) + 8 * (r2 >> 2) + 4 * hi;
        const float rr = __shfl(rsq, ro, 64);
        o_lo[r2] *= rr;
        o_hi[r2] *= rr;
      }
    }

#pragma unroll
    for (int r = 0; r < 16; r++) {
      sa[r] = exp2f(sa[r] - m_run);
      sb[r] = exp2f(sb[r] - m_run);
    }
    float s8[8];
#pragma unroll
    for (int i = 0; i < 8; i++)
      s8[i] = (sa[i] + sa[i + 8]) + (sb[i] + sb[i + 8]);
    float ps = ((s8[0] + s8[1]) + (s8[2] + s8[3])) + ((s8[4] + s8[5]) + (s8[6] + s8[7]));
    ps += __shfl_xor(ps, 32, 64);
    l_run += ps;
  };

  auto cvt_pv = [&](const bf16x8 vl[4], const bf16x8 vh[4]) {
    bf16x8 pa[4];
#pragma unroll
    for (int ks = 0; ks < 4; ks++) {
      const int c8 = (ks & 1) * 8;
      const f32x16& src = (ks < 2) ? sa : sb;
      unsigned int a0 = cvt_pk_bf16(src[c8 + 0], src[c8 + 1]);
      unsigned int b0 = cvt_pk_bf16(src[c8 + 4], src[c8 + 5]);
      unsigned int a1 = cvt_pk_bf16(src[c8 + 2], src[c8 + 3]);
      unsigned int b1 = cvt_pk_bf16(src[c8 + 6], src[c8 + 7]);
      plane32_swap(a0, b0);
      plane32_swap(a1, b1);
      pa[ks] = __builtin_bit_cast(bf16x8, u32x4{a0, a1, b0, b1});
    }
#pragma unroll
    for (int ks = 0; ks < 4; ks++) {
      o_lo = mfma32(pa[ks], vl[ks], o_lo);
      o_hi = mfma32(pa[ks], vh[ks], o_hi);
    }
  };

  // ---- prologue: K(s_base) + QK ----
  {
    const unsigned short* krA = kbase + (size_t)(s_base + q31) * 512;
    bf16x8 k0[8];
#pragma unroll
    for (int c = 0; c < 4; c++) {
      k0[c] = ld_bf8(krA + c * 16);
      k0[4 + c] = ld_bf8(krA + 32 * 512 + c * 16);
    }
    sa = mfma32(k0[0], qf0, z16); sb = mfma32(k0[4], qf0, z16);
    sa = mfma32(k0[1], qf1, sa);  sb = mfma32(k0[5], qf1, sb);
    sa = mfma32(k0[2], qf2, sa);  sb = mfma32(k0[6], qf2, sb);
    sa = mfma32(k0[3], qf3, sa);  sb = mfma32(k0[7], qf3, sb);
  }

  // ---- this wave's 8 tiles: 7 pipelined + tail ----
  for (int t = 0; t < 7; ++t) {
    const int s0 = s_base + t * 64;
    const int s1 = s0 + 64;
    bf16x8 kn[8];
    const unsigned short* krA = kbase + (size_t)(s1 + q31) * 512;
#pragma unroll
    for (int c = 0; c < 4; c++) {
      kn[c] = ld_bf8(krA + c * 16);
      kn[4 + c] = ld_bf8(krA + 32 * 512 + c * 16);
    }
    bf16x8 vl[4], vh[4];
#pragma unroll
    for (int ks = 0; ks < 4; ks++) {
      vl[ks] = ld_bf8(vb_lo + s0 + ks * 16);
      vh[ks] = ld_bf8(vb_hi + s0 + ks * 16);
    }

    softmax_part(s0);

    f32x16 sa_n, sb_n;
    sa_n = mfma32(kn[0], qf0, z16); sb_n = mfma32(kn[4], qf0, z16);
    sa_n = mfma32(kn[1], qf1, sa_n); sb_n = mfma32(kn[5], qf1, sb_n);
    sa_n = mfma32(kn[2], qf2, sa_n); sb_n = mfma32(kn[6], qf2, sb_n);
    sa_n = mfma32(kn[3], qf3, sa_n); sb_n = mfma32(kn[7], qf3, sb_n);

    cvt_pv(vl, vh);

    sa = sa_n; sb = sb_n;
  }

  {
    const int s0 = s_base + 448;
    bf16x8 vl[4], vh[4];
#pragma unroll
    for (int ks = 0; ks < 4; ks++) {
      vl[ks] = ld_bf8(vb_lo + s0 + ks * 16);
      vh[ks] = ld_bf8(vb_hi + s0 + ks * 16);
    }
    softmax_part(s0);
    cvt_pv(vl, vh);
  }

  // ---- write per-wave partials to LDS ----
#pragma unroll
  for (int r2 = 0; r2 < 16; r2++) {
    const int ro = (r2 & 3) + 8 * (r2 >> 2) + 4 * hi;
    o_lds[w][ro][q31] = o_lo[r2];
    o_lds[w][ro][32 + q31] = o_hi[r2];
  }
  if (hi == 0) {
    ml_lds[w][0][q31] = m_run;
    ml_lds[w][1][q31] = l_run;
  }
  __syncthreads();

  // ---- 4-way LSE combine -> bf16 At; thread = (col, 8 rows) ----
  const int col = tid & 63;
  const int r0 = (tid >> 6) * 8;
  for (int rr = 0; rr < 8; ++rr) {
    const int row = r0 + rr;
    const float m0 = ml_lds[0][0][row], m1 = ml_lds[1][0][row];
    const float m2 = ml_lds[2][0][row], m3 = ml_lds[3][0][row];
    const float mc = fmaxf(fmaxf(m0, m1), fmaxf(m2, m3));
    const float w0 = exp2f(m0 - mc), w1 = exp2f(m1 - mc);
    const float w2 = exp2f(m2 - mc), w3 = exp2f(m3 - mc);
    const float lc = fmaf(ml_lds[0][1][row], w0,
                     fmaf(ml_lds[1][1][row], w1,
                     fmaf(ml_lds[2][1][row], w2, ml_lds[3][1][row] * w3)));
    const float ov = fmaf(o_lds[0][row][col], w0,
                     fmaf(o_lds[1][row][col], w1,
                     fmaf(o_lds[2][row][col], w2, o_lds[3][row][col] * w3)));
    At[(size_t)(b * 2048 + q0w + row) * 512 + h * 64 + col] = f2bf(ov / lc);
  }
}

// ---------------- host ----------------
extern "C" void kernel_launch(void* const* d_in, const int* in_sizes, int n_in,
                              void* d_out, int out_size, void* d_ws, size_t ws_size,
                              hipStream_t stream) {
  const float* query = (const float*)d_in[0];
  const float* key   = (const float*)d_in[1];
  const float* value = (const float*)d_in[2];
  const float* Wq = (const float*)d_in[3];
  const float* bq = (const float*)d_in[4];
  const float* Wk = (const float*)d_in[5];
  const float* bk = (const float*)d_in[6];
  const float* Wv = (const float*)d_in[7];
  const float* bv = (const float*)d_in[8];
  const float* Wo = (const float*)d_in[9];
  const float* bo = (const float*)d_in[10];
  const float* rel = (const float*)d_in[11];

  char* ws = (char*)d_ws;
  const size_t SZX = (size_t)4 * 2048 * 512;
  const size_t SZW = (size_t)512 * 512;
  unsigned short* xq = (unsigned short*)ws;
  unsigned short* xk = xq + SZX;
  unsigned short* xv = xk + SZX;
  unsigned short* wq = xv + SZX;
  unsigned short* wk = wq + SZW;
  unsigned short* wv = wk + SZW;
  unsigned short* wo = wv + SZW;
  unsigned short* Qp = wo + SZW;
  unsigned short* Kp = Qp + SZX;
  unsigned short* Vt = Kp + SZX;
  unsigned short* At = Vt + SZX;

  auto cvt = [&](const float* s, unsigned short* dst, int n) {
    cvt_kernel<<<dim3((n + 1023) / 1024), dim3(256), 0, stream>>>(s, dst, n);
  };
  cvt(query, xq, (int)SZX);
  cvt(key, xk, (int)SZX);
  cvt(value, xv, (int)SZX);
  cvt(Wq, wq, (int)SZW);
  cvt(Wk, wk, (int)SZW);
  cvt(Wv, wv, (int)SZW);
  cvt(Wo, wo, (int)SZW);

  dim3 gg(4, 64), blk(256);
  gemm_bt<0><<<gg, blk, 0, stream>>>(xq, wq, bq, (void*)Qp);
  gemm_bt<0><<<gg, blk, 0, stream>>>(xk, wk, bk, (void*)Kp);
  gemm_bt<1><<<gg, blk, 0, stream>>>(xv, wv, bv, (void*)Vt);

  attn_kernel<<<dim3(2048), blk, 0, stream>>>(Qp, Kp, Vt, rel, At);

  gemm_bt<2><<<gg, blk, 0, stream>>>(At, wo, bo, d_out);
}